// Round 1
// 165.431 us; speedup vs baseline: 1.1412x; 1.1412x over previous
//
#include <hip/hip_runtime.h>
#include <stdint.h>

// tri_att: out[n,s] = sum_d w[n,d] * x[n,d,s]
//   w[n,d] = sum_c softmax_d( bilinear )[n,c,d]
//   bilinear[n,c,d] = sum_s softmax_s(7*x)[n,c,s] * x[n,d,s]
// NB=32, C=512, S=56*56=3136.
// R5: single f16 workspace array t = 7*(x - rowmax) replaces BOTH a (f_norm bf16)
// and b (x bf16):
//   A-frag = f16(exp(t))      (exp applied during reg-staged LDS fill)
//   B-frag = t (raw f16)
//   bilinear = inv7[c]*acc + mx[d]   since inv[c]*sum_s e = 1 exactly
//   k_out:  out = (sum_d w*t)/7 + sum_d w*mx[d]
// Saves 206 MB HBM (103 MB k_prep writes + 103 MB k_gemm reads); f16 beats bf16
// precision on both operands. MFMA: mfma_f32_16x16x32_f16 (same rate as bf16).

#define NB 32
#define CC 512
#define SS 3136
#define SCALE 7.0f

typedef float f32x4 __attribute__((ext_vector_type(4)));
typedef _Float16 f16x8 __attribute__((ext_vector_type(8)));
typedef _Float16 f16x4 __attribute__((ext_vector_type(4)));
typedef _Float16 f16x2 __attribute__((ext_vector_type(2)));

// ---------- helpers ----------
__device__ inline unsigned short f2bf(float f) {  // RNE float->bf16 bit pattern
  unsigned int u = __float_as_uint(f);
  u += 0x7fffu + ((u >> 16) & 1u);
  return (unsigned short)(u >> 16);
}
__device__ inline float bf2f(unsigned short u) {
  return __uint_as_float((uint32_t)u << 16);
}

__device__ inline float wredmax(float v) {
#pragma unroll
  for (int m = 32; m >= 1; m >>= 1) v = fmaxf(v, __shfl_xor(v, m, 64));
  return v;
}
__device__ inline float wredsum(float v) {
#pragma unroll
  for (int m = 32; m >= 1; m >>= 1) v += __shfl_xor(v, m, 64);
  return v;
}

__device__ inline void load_lds16(const void* g, void* l) {
  __builtin_amdgcn_global_load_lds(
      (const __attribute__((address_space(1))) void*)(uintptr_t)g,
      (__attribute__((address_space(3))) void*)(uintptr_t)l, 16, 0, 0);
}

// ---------- K1: t = f16(7*(x - rowmax)); inv7 = 1/(7*sum e_q); mx; zero esum ----
__global__ __launch_bounds__(256) void k_prep(const float* __restrict__ x,
                                              unsigned short* __restrict__ t,
                                              float* __restrict__ inv7,
                                              float* __restrict__ mxv,
                                              float* __restrict__ esum) {
  const int row = blockIdx.x;          // n*CC + c
  const int tid = threadIdx.x;
  if (tid == 0) esum[row] = 0.f;       // consumed by k_gemm (next kernel)
  const float4* xr = (const float4*)(x + (size_t)row * SS);
  float4 v0 = xr[tid];
  float4 v1 = xr[tid + 256];
  float4 v2 = xr[tid + 512];
  float4 v3 = (tid < 16) ? xr[768 + tid] : make_float4(-1e30f, -1e30f, -1e30f, -1e30f);

  float mx = fmaxf(fmaxf(fmaxf(v0.x, v0.y), fmaxf(v0.z, v0.w)),
             fmaxf(fmaxf(fmaxf(v1.x, v1.y), fmaxf(v1.z, v1.w)),
             fmaxf(fmaxf(fmaxf(v2.x, v2.y), fmaxf(v2.z, v2.w)),
                   fmaxf(fmaxf(v3.x, v3.y), fmaxf(v3.z, v3.w)))));
  __shared__ float redm[4], reds[4];
  mx = wredmax(mx);
  if ((tid & 63) == 0) redm[tid >> 6] = mx;
  __syncthreads();
  mx = fmaxf(fmaxf(redm[0], redm[1]), fmaxf(redm[2], redm[3]));

  // Quantize t to f16, and sum exp(t) with the EXACT rounding the GEMM's
  // A-operand will see: e_q = f16(expf(float(f16 t))).  Keeps inv*sum(e)=1.
  float s = 0.f;
  f16x4 p0, p1, p2, p3;
#define TQ(dst, sv)                                        \
  {                                                        \
    _Float16 th = (_Float16)(SCALE * ((sv) - mx));         \
    (dst) = th;                                            \
    s += (float)(_Float16)__expf((float)th);               \
  }
  TQ(p0[0], v0.x) TQ(p0[1], v0.y) TQ(p0[2], v0.z) TQ(p0[3], v0.w)
  TQ(p1[0], v1.x) TQ(p1[1], v1.y) TQ(p1[2], v1.z) TQ(p1[3], v1.w)
  TQ(p2[0], v2.x) TQ(p2[1], v2.y) TQ(p2[2], v2.z) TQ(p2[3], v2.w)
  TQ(p3[0], v3.x) TQ(p3[1], v3.y) TQ(p3[2], v3.z) TQ(p3[3], v3.w)
#undef TQ
  // dummy lanes (tid>=16) contribute expf(-inf)=0 to s and are never stored
  s = wredsum(s);
  if ((tid & 63) == 0) reds[tid >> 6] = s;
  __syncthreads();

  f16x4* tr = (f16x4*)(t + (size_t)row * SS);
  tr[tid] = p0;
  tr[tid + 256] = p1;
  tr[tid + 512] = p2;
  if (tid < 16) tr[768 + tid] = p3;
  if (tid == 0) {
    const float stot = reds[0] + reds[1] + reds[2] + reds[3];
    inv7[row] = 1.0f / (SCALE * stot);
    mxv[row] = mx;
  }
}

// ---------- K2: batched NT GEMM on t -> p = exp(bilinear) (bf16) + row exp-sum --
// 128x128 tile/block, BK=64, XOR-swizzled LDS.
// B staged via global_load_lds w16 (raw t); A reg-staged with exp() applied
// (same swizzled placement), so the MFMA sees A = f16(exp(t)), B = t.
// Epilogue: bilinear = inv7[c]*acc + mx[d]  (exact mx correction in f32).
// XCD swizzle: XCD x owns n in {4x..4x+3}.
#define BM 128
#define BK 64

__global__ __launch_bounds__(256) void k_gemm(const unsigned short* __restrict__ T,
                                              unsigned short* __restrict__ P,
                                              const float* __restrict__ inv7,
                                              const float* __restrict__ mxv,
                                              float* __restrict__ esum) {
  __shared__ unsigned short sA[BM * BK];  // 16 KB (holds exp(t) f16)
  __shared__ unsigned short sB[BM * BK];  // 16 KB (holds raw t f16)
  const int lin  = blockIdx.y * gridDim.x + blockIdx.x;  // 0..511
  const int xcd  = lin & 7;
  const int slot = lin >> 3;                 // 0..63
  const int pair = xcd * 16 + (slot >> 2);   // 0..127
  const int n    = pair >> 2;                // = xcd*4 + (slot>>4)
  const int tm   = (pair & 3) * BM;
  const int tn   = (slot & 3) * BM;
  const unsigned short* Ap = T + (size_t)n * CC * SS + (size_t)tm * SS;
  const unsigned short* Bp = T + (size_t)n * CC * SS + (size_t)tn * SS;
  const int tid  = threadIdx.x;
  const int lane = tid & 63;
  const int wave = tid >> 6;
  const int wm   = (wave >> 1) * 64;
  const int wn   = (wave & 1) * 64;
  const int quad = lane >> 4;
  const int rr   = lane & 15;

  f32x4 acc[4][4] = {};

  for (int k0 = 0; k0 < SS; k0 += BK) {
    f16x8 hv[4];
#pragma unroll
    for (int tt = 0; tt < 4; tt++) {
      const int j  = ((tt << 2) + wave) * 64 + lane;
      const int r  = j >> 3;
      const int cg = (j & 7) ^ (r & 7);
      hv[tt] = *(const f16x8*)(Ap + (size_t)r * SS + (k0 + cg * 8));  // A -> regs
      load_lds16(Bp + (size_t)r * SS + (k0 + cg * 8), &sB[(size_t)j * 8]);  // B direct
    }
#pragma unroll
    for (int tt = 0; tt < 4; tt++) {
      const int j = ((tt << 2) + wave) * 64 + lane;
      f16x8 ev;
#pragma unroll
      for (int u = 0; u < 8; u++) ev[u] = (_Float16)__expf((float)hv[tt][u]);
      *(f16x8*)&sA[(size_t)j * 8] = ev;  // same swizzled placement as gload_lds
    }
    __syncthreads();
#pragma unroll
    for (int ki = 0; ki < 2; ki++) {
      f16x8 af[4], bfr[4];
      const int cg = ki * 4 + quad;
#pragma unroll
      for (int mt = 0; mt < 4; mt++) {
        const int r  = wm + mt * 16 + rr;
        const int cs = cg ^ (r & 7);
        af[mt] = *(const f16x8*)&sA[(r * 8 + cs) * 8];
      }
#pragma unroll
      for (int nt = 0; nt < 4; nt++) {
        const int r  = wn + nt * 16 + rr;
        const int cs = cg ^ (r & 7);
        bfr[nt] = *(const f16x8*)&sB[(r * 8 + cs) * 8];
      }
#pragma unroll
      for (int mt = 0; mt < 4; mt++)
#pragma unroll
        for (int nt = 0; nt < 4; nt++)
          acc[mt][nt] = __builtin_amdgcn_mfma_f32_16x16x32_f16(af[mt], bfr[nt], acc[mt][nt], 0, 0, 0);
    }
    __syncthreads();
  }

  // Epilogue: bl = inv7[c]*acc + mx[d]; p = exp(bl) stored bf16 (|bl| <= ~5.5);
  // esum[n,row] += row-sums via quad shuffle-reduce + XCD-local atomics.
  // C/D layout: col = lane&15, row = quad*4 + reg.
  unsigned short* Pp = P + ((size_t)n << 18);
  float mxd[4];
#pragma unroll
  for (int nt = 0; nt < 4; nt++) mxd[nt] = mxv[n * CC + tn + wn + nt * 16 + rr];
#pragma unroll
  for (int mt = 0; mt < 4; mt++) {
    const int rbase = tm + wm + mt * 16 + quad * 4;
    float iv[4];
#pragma unroll
    for (int i = 0; i < 4; i++) iv[i] = inv7[n * CC + rbase + i];
    float rs[4] = {0.f, 0.f, 0.f, 0.f};
#pragma unroll
    for (int nt = 0; nt < 4; nt++) {
      const int col = tn + wn + nt * 16 + rr;
#pragma unroll
      for (int i = 0; i < 4; i++) {
        const float e = __expf(acc[mt][nt][i] * iv[i] + mxd[nt]);
        rs[i] += e;
        Pp[(size_t)(rbase + i) * CC + col] = f2bf(e);
      }
    }
#pragma unroll
    for (int i = 0; i < 4; i++) {
      float v = rs[i];
#pragma unroll
      for (int m = 8; m >= 1; m >>= 1) v += __shfl_xor(v, m, 64);  // reduce rr
      if (rr == 0) atomicAdd(&esum[n * CC + rbase + i], v);
    }
  }
}

// ---------- K3: wp[n,g,d] = sum_{c in group g} p[n,c,d] / esum[n,c]; zero out ----
// 512 blocks, XCD-aligned with gemm's n->XCD mapping (p reads hit local L2).
__global__ __launch_bounds__(256) void k_wsum(const unsigned short* __restrict__ P,
                                              const float* __restrict__ esum,
                                              float* __restrict__ wp,
                                              float* __restrict__ outz) {
  const int lin  = blockIdx.y * gridDim.x + blockIdx.x;  // 0..511
  const int xcd  = lin & 7;
  const int slot = lin >> 3;           // 0..63
  const int n    = xcd * 4 + (slot & 3);
  const int g    = (slot >> 2) & 7;    // c-group of 64
  const int d    = (slot >> 5) * 256 + threadIdx.x;
  __shared__ float sinv[64];
  if (threadIdx.x < 64) sinv[threadIdx.x] = 1.0f / esum[n * CC + g * 64 + threadIdx.x];
  __syncthreads();
  const unsigned short* p = P + (size_t)n * CC * CC + (size_t)(g * 64) * CC + d;
  float acc = 0.f;
#pragma unroll 8
  for (int c = 0; c < 64; c++) acc += bf2f(p[(size_t)c * CC]) * sinv[c];
  wp[((size_t)n * 8 + g) * CC + d] = acc;
  // zero out[] for k_out's atomics (512*256 = 131072 >= NB*SS = 100352)
  const int idx = lin * 256 + threadIdx.x;
  if (idx < NB * SS) outz[idx] = 0.f;
}

// ---------- K4: out[n,s] += (1/7)*sum_{d in quarter} w[n,d]*t[n,d,s] + sum w*mx --
__global__ __launch_bounds__(256) void k_out(const unsigned short* __restrict__ T,
                                             const float* __restrict__ wp,
                                             const float* __restrict__ mxv,
                                             float* __restrict__ out) {
  const int n  = blockIdx.y >> 2;
  const int dq = blockIdx.y & 3;        // d-quarter of 128
  const int s0 = (blockIdx.x * 256 + threadIdx.x) * 2;
  __shared__ float sw[128];
  __shared__ float sc[2];
  if (threadIdx.x < 128) {
    float v = 0.f;
#pragma unroll
    for (int g = 0; g < 8; g++) v += wp[((size_t)n * 8 + g) * CC + dq * 128 + threadIdx.x];
    sw[threadIdx.x] = v * (1.0f / SCALE);                    // folds the /7
    float pm = v * mxv[n * CC + dq * 128 + threadIdx.x];     // w[d]*mx[d]
    pm = wredsum(pm);
    if ((threadIdx.x & 63) == 0) sc[threadIdx.x >> 6] = pm;
  }
  __syncthreads();
  const float csum = sc[0] + sc[1];     // this quarter's sum_d w[d]*mx[d]
  if (s0 >= SS) return;
  const unsigned short* bp = T + (size_t)n * CC * SS + (size_t)(dq * 128) * SS + s0;
  float a0 = 0.f, a1 = 0.f;
#pragma unroll 8
  for (int d = 0; d < 128; d++) {
    const f16x2 hv = *(const f16x2*)(bp + (size_t)d * SS);
    a0 += sw[d] * (float)hv[0];
    a1 += sw[d] * (float)hv[1];
  }
  atomicAdd(&out[(size_t)n * SS + s0], a0 + csum);
  atomicAdd(&out[(size_t)n * SS + s0 + 1], a1 + csum);
}

extern "C" void kernel_launch(void* const* d_in, const int* in_sizes, int n_in,
                              void* d_out, int out_size, void* d_ws, size_t ws_size,
                              hipStream_t stream) {
  const float* x = (const float*)d_in[0];
  float* out = (float*)d_out;
  char* ws = (char*)d_ws;
  // ws: t(f16) 102,760,448 | p(bf16) 16,777,216 | esum 65,536 | inv7 65,536
  //     | mx 65,536 | wp 524,288   (total ~120.3 MB)
  unsigned short* t    = (unsigned short*)ws;
  unsigned short* pmat = (unsigned short*)(ws + 102760448ull);
  float* esum = (float*)(ws + 119537664ull);
  float* inv7 = (float*)(ws + 119603200ull);
  float* mxv  = (float*)(ws + 119668736ull);
  float* wp   = (float*)(ws + 119734272ull);

  hipLaunchKernelGGL(k_prep, dim3(NB * CC),   dim3(256), 0, stream, x, t, inv7, mxv, esum);
  hipLaunchKernelGGL(k_gemm, dim3(16, NB),    dim3(256), 0, stream, t, pmat, inv7, mxv, esum);
  hipLaunchKernelGGL(k_wsum, dim3(16, NB),    dim3(256), 0, stream, pmat, esum, wp, out);
  hipLaunchKernelGGL(k_out,  dim3(7, NB * 4), dim3(256), 0, stream, t, wp, mxv, out);
}

// Round 2
// 145.863 us; speedup vs baseline: 1.2943x; 1.1342x over previous
//
#include <hip/hip_runtime.h>
#include <stdint.h>

// tri_att: out[n,s] = sum_d w[n,d] * x[n,d,s]
//   w[n,d] = sum_c softmax_d( bilinear )[n,c,d]
//   bilinear[n,c,d] = sum_s softmax_s(7*x)[n,c,s] * x[n,d,s]
// NB=32, C=512, S=56*56=3136.
// R6: t' = 7*log2e*(x - rowmax) f16 (exp2-domain):
//   A-frag = f16(exp2(t'))  via raw v_exp_f32 + v_cvt_pkrtz (no mul, pair-pack)
//   B-frag = t'
//   bilinear = inv7[c]*acc + mx[d],  inv7 = 1/(7*log2e*S_c)
//   k_out:  out = (1/(7*log2e))*sum_d w*t' + sum_d w*mx[d]
// GEMM restructured: double-buffered LDS (64 KB), ONE __syncthreads per K-step,
// T14 issue-early (A->reg + B gload_lds for t+1 issued before MFMA on t; exp+
// ds_write after MFMA). Barrier's vmcnt(0)/lgkm(0) drain = the only sync needed.

#define NB 32
#define CC 512
#define SS 3136
#define SCALE 7.0f
#define K7F 10.098865286222744f     // 7*log2(e)
#define INVK7F 0.09902102579427789f // 1/K7F

typedef float f32x4 __attribute__((ext_vector_type(4)));
typedef _Float16 f16x8 __attribute__((ext_vector_type(8)));
typedef _Float16 f16x4 __attribute__((ext_vector_type(4)));
typedef _Float16 f16x2 __attribute__((ext_vector_type(2)));

// ---------- helpers ----------
__device__ inline unsigned short f2bf(float f) {  // RNE float->bf16 bit pattern
  unsigned int u = __float_as_uint(f);
  u += 0x7fffu + ((u >> 16) & 1u);
  return (unsigned short)(u >> 16);
}
__device__ inline float bf2f(unsigned short u) {
  return __uint_as_float((uint32_t)u << 16);
}

__device__ inline float fast_exp2(float v) {  // v_exp_f32 = 2^x
  float r;
  asm("v_exp_f32 %0, %1" : "=v"(r) : "v"(v));
  return r;
}
__device__ inline uint32_t pk2h(float a, float b) {  // 2xf32 -> packed 2xf16 (RTZ)
  uint32_t r;
  asm("v_cvt_pkrtz_f16_f32 %0, %1, %2" : "=v"(r) : "v"(a), "v"(b));
  return r;
}
__device__ inline f16x8 exp2_f16x8(f16x8 h) {  // elementwise f16(2^h)
  f16x8 r;
#pragma unroll
  for (int q = 0; q < 4; q++) {
    const float e0 = fast_exp2((float)h[2 * q]);
    const float e1 = fast_exp2((float)h[2 * q + 1]);
    ((uint32_t*)&r)[q] = pk2h(e0, e1);
  }
  return r;
}

__device__ inline float wredmax(float v) {
#pragma unroll
  for (int m = 32; m >= 1; m >>= 1) v = fmaxf(v, __shfl_xor(v, m, 64));
  return v;
}
__device__ inline float wredsum(float v) {
#pragma unroll
  for (int m = 32; m >= 1; m >>= 1) v += __shfl_xor(v, m, 64);
  return v;
}

__device__ inline void load_lds16(const void* g, void* l) {
  __builtin_amdgcn_global_load_lds(
      (const __attribute__((address_space(1))) void*)(uintptr_t)g,
      (__attribute__((address_space(3))) void*)(uintptr_t)l, 16, 0, 0);
}

// ---------- K1: t' = f16(K7*(x - rowmax)); inv7 = 1/(K7*sum e_q); mx; zero esum -
__global__ __launch_bounds__(256) void k_prep(const float* __restrict__ x,
                                              unsigned short* __restrict__ t,
                                              float* __restrict__ inv7,
                                              float* __restrict__ mxv,
                                              float* __restrict__ esum) {
  const int row = blockIdx.x;          // n*CC + c
  const int tid = threadIdx.x;
  if (tid == 0) esum[row] = 0.f;       // consumed by k_gemm (next kernel)
  const float4* xr = (const float4*)(x + (size_t)row * SS);
  float4 v0 = xr[tid];
  float4 v1 = xr[tid + 256];
  float4 v2 = xr[tid + 512];
  float4 v3 = (tid < 16) ? xr[768 + tid] : make_float4(-1e30f, -1e30f, -1e30f, -1e30f);

  float mx = fmaxf(fmaxf(fmaxf(v0.x, v0.y), fmaxf(v0.z, v0.w)),
             fmaxf(fmaxf(fmaxf(v1.x, v1.y), fmaxf(v1.z, v1.w)),
             fmaxf(fmaxf(fmaxf(v2.x, v2.y), fmaxf(v2.z, v2.w)),
                   fmaxf(fmaxf(v3.x, v3.y), fmaxf(v3.z, v3.w)))));
  __shared__ float redm[4], reds[4];
  mx = wredmax(mx);
  if ((tid & 63) == 0) redm[tid >> 6] = mx;
  __syncthreads();
  mx = fmaxf(fmaxf(redm[0], redm[1]), fmaxf(redm[2], redm[3]));

  // Quantize t' to f16 and sum exp2(t') with EXACTLY the rounding the GEMM's
  // A-operand will see (v_exp_f32 + v_cvt_pkrtz).  Keeps inv*sum(e)=1.
  float s = 0.f;
  f16x4 p0, p1, p2, p3;
#define TQ2(dst, i0, a0, a1)                                  \
  {                                                           \
    _Float16 h0 = (_Float16)(K7F * ((a0) - mx));              \
    _Float16 h1 = (_Float16)(K7F * ((a1) - mx));              \
    dst[i0] = h0; dst[i0 + 1] = h1;                           \
    uint32_t u = pk2h(fast_exp2((float)h0), fast_exp2((float)h1)); \
    f16x2 e2; *(uint32_t*)&e2 = u;                            \
    s += (float)e2[0] + (float)e2[1];                         \
  }
  TQ2(p0, 0, v0.x, v0.y) TQ2(p0, 2, v0.z, v0.w)
  TQ2(p1, 0, v1.x, v1.y) TQ2(p1, 2, v1.z, v1.w)
  TQ2(p2, 0, v2.x, v2.y) TQ2(p2, 2, v2.z, v2.w)
  TQ2(p3, 0, v3.x, v3.y) TQ2(p3, 2, v3.z, v3.w)
#undef TQ2
  // dummy lanes (tid>=16): t' = -inf -> exp2 = 0 contribution, never stored
  s = wredsum(s);
  if ((tid & 63) == 0) reds[tid >> 6] = s;
  __syncthreads();

  f16x4* tr = (f16x4*)(t + (size_t)row * SS);
  tr[tid] = p0;
  tr[tid + 256] = p1;
  tr[tid + 512] = p2;
  if (tid < 16) tr[768 + tid] = p3;
  if (tid == 0) {
    const float stot = reds[0] + reds[1] + reds[2] + reds[3];
    inv7[row] = 1.0f / (K7F * stot);
    mxv[row] = mx;
  }
}

// ---------- K2: batched NT GEMM on t' -> p = exp(bilinear) (bf16) + row exp-sum -
// 128x128 tile/block, BK=64, XOR-swizzled double-buffered LDS (64 KB).
// Per K-step: issue A(t+1)->reg + B(t+1) gload_lds -> [nxt]; ds_read+MFMA on
// [cur]; exp2(A-regs)->ds_write sA[nxt]; ONE __syncthreads (drains vm+lgkm).
// XCD swizzle: XCD x owns n in {4x..4x+3}.
#define BM 128
#define BK 64
#define NT (SS / BK)  // 49

__global__ __launch_bounds__(256, 2) void k_gemm(const unsigned short* __restrict__ T,
                                                 unsigned short* __restrict__ P,
                                                 const float* __restrict__ inv7,
                                                 const float* __restrict__ mxv,
                                                 float* __restrict__ esum) {
  __shared__ unsigned short sA[2][BM * BK];  // 2 x 16 KB (exp2(t') f16)
  __shared__ unsigned short sB[2][BM * BK];  // 2 x 16 KB (raw t' f16)
  const int lin  = blockIdx.y * gridDim.x + blockIdx.x;  // 0..511
  const int xcd  = lin & 7;
  const int slot = lin >> 3;                 // 0..63
  const int pair = xcd * 16 + (slot >> 2);   // 0..127
  const int n    = pair >> 2;                // = xcd*4 + (slot>>4)
  const int tm   = (pair & 3) * BM;
  const int tn   = (slot & 3) * BM;
  const unsigned short* Ap = T + (size_t)n * CC * SS + (size_t)tm * SS;
  const unsigned short* Bp = T + (size_t)n * CC * SS + (size_t)tn * SS;
  const int tid  = threadIdx.x;
  const int lane = tid & 63;
  const int wave = tid >> 6;
  const int wm   = (wave >> 1) * 64;
  const int wn   = (wave & 1) * 64;
  const int quad = lane >> 4;
  const int rr   = lane & 15;

  // Per-thread staging geometry (constant over K-steps).
  int jb[4];                      // LDS element offset = j*8 (swizzle-matched)
  const unsigned short *Aaddr[4], *Baddr[4];
#pragma unroll
  for (int tt = 0; tt < 4; tt++) {
    const int j  = ((tt << 2) + wave) * 64 + lane;
    const int r  = j >> 3;
    const int cg = (j & 7) ^ (r & 7);
    jb[tt]   = j * 8;
    Aaddr[tt] = Ap + (size_t)r * SS + cg * 8;
    Baddr[tt] = Bp + (size_t)r * SS + cg * 8;
  }

  f32x4 acc[4][4] = {};

#define COMPUTE(BUF)                                                          \
  {                                                                           \
    _Pragma("unroll")                                                         \
    for (int ki = 0; ki < 2; ki++) {                                          \
      f16x8 af[4], bfr[4];                                                    \
      const int cg = ki * 4 + quad;                                           \
      _Pragma("unroll")                                                       \
      for (int mt = 0; mt < 4; mt++) {                                        \
        const int r  = wm + mt * 16 + rr;                                     \
        const int cs = cg ^ (r & 7);                                          \
        af[mt] = *(const f16x8*)&sA[BUF][(r * 8 + cs) * 8];                   \
      }                                                                       \
      _Pragma("unroll")                                                       \
      for (int nt = 0; nt < 4; nt++) {                                        \
        const int r  = wn + nt * 16 + rr;                                     \
        const int cs = cg ^ (r & 7);                                          \
        bfr[nt] = *(const f16x8*)&sB[BUF][(r * 8 + cs) * 8];                  \
      }                                                                       \
      _Pragma("unroll")                                                       \
      for (int mt = 0; mt < 4; mt++)                                          \
        _Pragma("unroll")                                                     \
        for (int nt = 0; nt < 4; nt++)                                        \
          acc[mt][nt] = __builtin_amdgcn_mfma_f32_16x16x32_f16(               \
              af[mt], bfr[nt], acc[mt][nt], 0, 0, 0);                         \
    }                                                                         \
  }

  // Prologue: stage tile 0 into buffer 0.
  {
    f16x8 hv[4];
#pragma unroll
    for (int tt = 0; tt < 4; tt++) hv[tt] = *(const f16x8*)Aaddr[tt];
#pragma unroll
    for (int tt = 0; tt < 4; tt++) load_lds16(Baddr[tt], &sB[0][jb[tt]]);
#pragma unroll
    for (int tt = 0; tt < 4; tt++) *(f16x8*)&sA[0][jb[tt]] = exp2_f16x8(hv[tt]);
    __syncthreads();
  }

  int cur = 0;
  for (int t = 0; t < NT - 1; t++) {
    const int koff = (t + 1) * BK;
    const int nxt  = cur ^ 1;
    // Issue-early: next tile's A->regs, B->LDS[nxt] (latency hides under MFMA).
    f16x8 hvN[4];
#pragma unroll
    for (int tt = 0; tt < 4; tt++) hvN[tt] = *(const f16x8*)(Aaddr[tt] + koff);
#pragma unroll
    for (int tt = 0; tt < 4; tt++) load_lds16(Baddr[tt] + koff, &sB[nxt][jb[tt]]);

    COMPUTE(cur);

#pragma unroll
    for (int tt = 0; tt < 4; tt++) *(f16x8*)&sA[nxt][jb[tt]] = exp2_f16x8(hvN[tt]);
    __syncthreads();  // drains vmcnt (gload_lds) + lgkm (ds_write) for [nxt]
    cur = nxt;
  }
  COMPUTE(cur);  // final tile; epilogue touches no LDS -> no barrier needed

  // Epilogue: bl = inv7[c]*acc + mx[d]; p = exp(bl) stored bf16 (|bl| <= ~5.5);
  // esum[n,row] += row-sums via quad shuffle-reduce + XCD-local atomics.
  // C/D layout: col = lane&15, row = quad*4 + reg.
  unsigned short* Pp = P + ((size_t)n << 18);
  float mxd[4];
#pragma unroll
  for (int nt = 0; nt < 4; nt++) mxd[nt] = mxv[n * CC + tn + wn + nt * 16 + rr];
#pragma unroll
  for (int mt = 0; mt < 4; mt++) {
    const int rbase = tm + wm + mt * 16 + quad * 4;
    float iv[4];
#pragma unroll
    for (int i = 0; i < 4; i++) iv[i] = inv7[n * CC + rbase + i];
    float rs[4] = {0.f, 0.f, 0.f, 0.f};
#pragma unroll
    for (int nt = 0; nt < 4; nt++) {
      const int col = tn + wn + nt * 16 + rr;
#pragma unroll
      for (int i = 0; i < 4; i++) {
        const float e = __expf(acc[mt][nt][i] * iv[i] + mxd[nt]);
        rs[i] += e;
        Pp[(size_t)(rbase + i) * CC + col] = f2bf(e);
      }
    }
#pragma unroll
    for (int i = 0; i < 4; i++) {
      float v = rs[i];
#pragma unroll
      for (int m = 8; m >= 1; m >>= 1) v += __shfl_xor(v, m, 64);  // reduce rr
      if (rr == 0) atomicAdd(&esum[n * CC + rbase + i], v);
    }
  }
#undef COMPUTE
}

// ---------- K3: wp[n,g,d] = sum_{c in group g} p[n,c,d] / esum[n,c]; zero out ----
// 512 blocks, XCD-aligned with gemm's n->XCD mapping (p reads hit local L2).
__global__ __launch_bounds__(256) void k_wsum(const unsigned short* __restrict__ P,
                                              const float* __restrict__ esum,
                                              float* __restrict__ wp,
                                              float* __restrict__ outz) {
  const int lin  = blockIdx.y * gridDim.x + blockIdx.x;  // 0..511
  const int xcd  = lin & 7;
  const int slot = lin >> 3;           // 0..63
  const int n    = xcd * 4 + (slot & 3);
  const int g    = (slot >> 2) & 7;    // c-group of 64
  const int d    = (slot >> 5) * 256 + threadIdx.x;
  __shared__ float sinv[64];
  if (threadIdx.x < 64) sinv[threadIdx.x] = 1.0f / esum[n * CC + g * 64 + threadIdx.x];
  __syncthreads();
  const unsigned short* p = P + (size_t)n * CC * CC + (size_t)(g * 64) * CC + d;
  float acc = 0.f;
#pragma unroll 8
  for (int c = 0; c < 64; c++) acc += bf2f(p[(size_t)c * CC]) * sinv[c];
  wp[((size_t)n * 8 + g) * CC + d] = acc;
  // zero out[] for k_out's atomics (512*256 = 131072 >= NB*SS = 100352)
  const int idx = lin * 256 + threadIdx.x;
  if (idx < NB * SS) outz[idx] = 0.f;
}

// ---------- K4: out[n,s] += (1/K7)*sum_{d in quarter} w[n,d]*t'[n,d,s] + sum w*mx
__global__ __launch_bounds__(256) void k_out(const unsigned short* __restrict__ T,
                                             const float* __restrict__ wp,
                                             const float* __restrict__ mxv,
                                             float* __restrict__ out) {
  const int n  = blockIdx.y >> 2;
  const int dq = blockIdx.y & 3;        // d-quarter of 128
  const int s0 = (blockIdx.x * 256 + threadIdx.x) * 2;
  __shared__ float sw[128];
  __shared__ float sc[2];
  if (threadIdx.x < 128) {
    float v = 0.f;
#pragma unroll
    for (int g = 0; g < 8; g++) v += wp[((size_t)n * 8 + g) * CC + dq * 128 + threadIdx.x];
    sw[threadIdx.x] = v * INVK7F;                            // folds 1/(7*log2e)
    float pm = v * mxv[n * CC + dq * 128 + threadIdx.x];     // w[d]*mx[d]
    pm = wredsum(pm);
    if ((threadIdx.x & 63) == 0) sc[threadIdx.x >> 6] = pm;
  }
  __syncthreads();
  const float csum = sc[0] + sc[1];     // this quarter's sum_d w[d]*mx[d]
  if (s0 >= SS) return;
  const unsigned short* bp = T + (size_t)n * CC * SS + (size_t)(dq * 128) * SS + s0;
  float a0 = 0.f, a1 = 0.f;
#pragma unroll 8
  for (int d = 0; d < 128; d++) {
    const f16x2 hv = *(const f16x2*)(bp + (size_t)d * SS);
    a0 += sw[d] * (float)hv[0];
    a1 += sw[d] * (float)hv[1];
  }
  atomicAdd(&out[(size_t)n * SS + s0], a0 + csum);
  atomicAdd(&out[(size_t)n * SS + s0 + 1], a1 + csum);
}

extern "C" void kernel_launch(void* const* d_in, const int* in_sizes, int n_in,
                              void* d_out, int out_size, void* d_ws, size_t ws_size,
                              hipStream_t stream) {
  const float* x = (const float*)d_in[0];
  float* out = (float*)d_out;
  char* ws = (char*)d_ws;
  // ws: t(f16) 102,760,448 | p(bf16) 16,777,216 | esum 65,536 | inv7 65,536
  //     | mx 65,536 | wp 524,288   (total ~120.3 MB)
  unsigned short* t    = (unsigned short*)ws;
  unsigned short* pmat = (unsigned short*)(ws + 102760448ull);
  float* esum = (float*)(ws + 119537664ull);
  float* inv7 = (float*)(ws + 119603200ull);
  float* mxv  = (float*)(ws + 119668736ull);
  float* wp   = (float*)(ws + 119734272ull);

  hipLaunchKernelGGL(k_prep, dim3(NB * CC),   dim3(256), 0, stream, x, t, inv7, mxv, esum);
  hipLaunchKernelGGL(k_gemm, dim3(16, NB),    dim3(256), 0, stream, t, pmat, inv7, mxv, esum);
  hipLaunchKernelGGL(k_wsum, dim3(16, NB),    dim3(256), 0, stream, pmat, esum, wp, out);
  hipLaunchKernelGGL(k_out,  dim3(7, NB * 4), dim3(256), 0, stream, t, wp, mxv, out);
}